// Round 4
// baseline (1250.128 us; speedup 1.0000x reference)
//
#include <hip/hip_runtime.h>
#include <stdint.h>

typedef unsigned long long u64;
typedef unsigned short u16;
typedef __attribute__((ext_vector_type(8))) short short8;
typedef __attribute__((ext_vector_type(4))) float f32x4;

// Problem constants
#define NB   16
#define NT   12
#define BTc  192     // NB*NT
#define NN   4096
#define DD   64
#define MM   128
#define TOPK 32
#define CAP  192     // candidate capacity (expected ~89, +7sigma margin; R2-proven)
#define NCH  6       // CAP/32 chunks

// d_out float offsets (outputs concatenated flat)
#define SEL1_OFF 0ULL
#define SEL2_OFF 50331648ULL
#define BIDX_OFF 100663296ULL
#define TIDX_OFF 101449728ULL
#define IDX_OFF  102236160ULL
// bf16 logits scratch (201.3 MB) occupies exactly the SEL1 float region.
// k2 reads row r's logits (8 KB) then writes row r's sel1 (same 8 KB) — per-row
// exclusive (row r is owned by exactly one wave), no cross-block overlap.

__device__ __forceinline__ unsigned ord32(float f) {
    unsigned u = __float_as_uint(f);
    return (u & 0x80000000u) ? ~u : (u | 0x80000000u);
}
__device__ __forceinline__ u16 f2bf(float f) {   // RNE round to bf16
    unsigned u = __float_as_uint(f);
    unsigned r = u + 0x7FFFu + ((u >> 16) & 1u);
    return (u16)(r >> 16);
}
__device__ __forceinline__ float bf2f(short s) {
    return __uint_as_float(((unsigned)(u16)s) << 16);
}
__device__ __forceinline__ u64 pack4bf(float4 v) {
    return (u64)f2bf(v.x) | ((u64)f2bf(v.y) << 16) |
           ((u64)f2bf(v.z) << 32) | ((u64)f2bf(v.w) << 48);
}
__device__ __forceinline__ void lds_fence() {
    asm volatile("s_waitcnt lgkmcnt(0)" ::: "memory");
    __builtin_amdgcn_sched_barrier(0);   // rule #18: pin against hoisting
}

// ---------------------------------------------------------------------------
// K1: approx logits via bf16 MFMA (unchanged — at its BW floor, ~105 us).
// ---------------------------------------------------------------------------
__global__ __launch_bounds__(256) void k1_logits_bf16(const float* __restrict__ nv1,
                                                      const float* __restrict__ nv2,
                                                      const float* __restrict__ emb,
                                                      u16* __restrict__ logitsB) {
    __shared__ u16 Als[128 * 128];   // 32 KB, [m][k] swizzled
    __shared__ u16 Bls[128 * 128];   // 32 KB, [n][k] swizzled (B^T layout)

    const int tid = threadIdx.x;
    const int nt  = blockIdx.x;      // 0..31
    const int bt  = blockIdx.y;      // 0..191
    const int n0  = nt * 128;

#pragma unroll
    for (int it = 0; it < 16; ++it) {
        int f4  = it * 256 + tid;
        int row = f4 >> 5;           // m
        int kq  = f4 & 31;
        float4 a = *(const float4*)(emb + row * 128 + kq * 4);
        int byte = row * 256 + ((kq * 8) ^ ((row & 7) << 4));
        *(u64*)((char*)Als + byte) = pack4bf(a);
    }
#pragma unroll
    for (int it = 0; it < 16; ++it) {
        int f4  = it * 256 + tid;
        int row = f4 >> 5;           // n within tile
        int kq  = f4 & 31;
        const float* src = (kq < 16)
            ? (nv1 + ((size_t)bt * NN + n0 + row) * DD + kq * 4)
            : (nv2 + ((size_t)bt * NN + n0 + row) * DD + (kq - 16) * 4);
        float4 bv = *(const float4*)src;
        int byte = row * 256 + ((kq * 8) ^ ((row & 7) << 4));
        *(u64*)((char*)Bls + byte) = pack4bf(bv);
    }
    __syncthreads();

    const int w  = tid >> 6;
    const int l  = tid & 63;
    const int mb = (w >> 1) * 64;
    const int nb = (w & 1) * 64;
    const int xr = (l & 7) << 4;

    f32x4 acc[4][4];
#pragma unroll
    for (int mi = 0; mi < 4; ++mi)
#pragma unroll
        for (int ni = 0; ni < 4; ++ni) acc[mi][ni] = {0.f, 0.f, 0.f, 0.f};

#pragma unroll
    for (int ks = 0; ks < 4; ++ks) {
        const int kb = (ks * 64 + (l >> 4) * 16) ^ xr;
        short8 a[4], b[4];
#pragma unroll
        for (int mi = 0; mi < 4; ++mi) {
            int row = mb + mi * 16 + (l & 15);
            a[mi] = *(const short8*)((const char*)Als + row * 256 + kb);
        }
#pragma unroll
        for (int ni = 0; ni < 4; ++ni) {
            int row = nb + ni * 16 + (l & 15);
            b[ni] = *(const short8*)((const char*)Bls + row * 256 + kb);
        }
#pragma unroll
        for (int mi = 0; mi < 4; ++mi)
#pragma unroll
            for (int ni = 0; ni < 4; ++ni)
                acc[mi][ni] = __builtin_amdgcn_mfma_f32_16x16x32_bf16(
                    a[mi], b[ni], acc[mi][ni], 0, 0, 0);
    }

    const size_t rbase = (size_t)bt * MM * NN;
#pragma unroll
    for (int mi = 0; mi < 4; ++mi)
#pragma unroll
        for (int ni = 0; ni < 4; ++ni) {
            int n = n0 + nb + ni * 16 + (l & 15);
#pragma unroll
            for (int r = 0; r < 4; ++r) {
                int m = mb + mi * 16 + (l >> 4) * 4 + r;
                logitsB[rbase + (size_t)m * NN + n] = f2bf(acc[mi][ni][r]);
            }
        }
}

// ---------------------------------------------------------------------------
// K2 (fused): per row (one wave, wave-private LDS, no __syncthreads):
//  1. scan bf16 logits row, 48th-lane-max threshold -> candidate superset
//  2. coalesced LDS-staged gather of candidate nv rows; exact seq-fmaf fp32 dot
//  3. pop exact top-32 (desc, ties -> lower index)
//  4. write idx/batch/time AND gather+write sel1/sel2 (winner rows L2-hot)
// ---------------------------------------------------------------------------
#define STG_STRIDE 68   // floats; 272 B row stride: 16B-aligned, ~4-way read conflict

__global__ __launch_bounds__(256) void k2_fused(const u16* logitsB,
                                                const float* __restrict__ nv1,
                                                const float* __restrict__ nv2,
                                                const float* __restrict__ emb,
                                                float* out) {
    const int tid = threadIdx.x;
    const int l   = tid & 63;
    const int w   = tid >> 6;
    const int row = blockIdx.x * 4 + w;   // 0..24575
    const int bt  = row >> 7;
    const int m   = row & 127;
    const u16* src = logitsB + (size_t)row * NN;

    __shared__ float stg[4][32 * STG_STRIDE];  // 8704 B per wave
    __shared__ int   cand[4][CAP];
    __shared__ float embrow[4][128];
    __shared__ int   widx[4][TOPK];

    embrow[w][l]      = emb[m * 128 + l];
    embrow[w][l + 64] = emb[m * 128 + 64 + l];

    // ---- 1. scan row (64 bf16 per lane in regs) + lane max ----
    short8 ch[8];
    float lmax = -INFINITY;
#pragma unroll
    for (int j = 0; j < 8; ++j) {
        ch[j] = *(const short8*)(src + j * 512 + l * 8);
#pragma unroll
        for (int e = 0; e < 8; ++e) lmax = fmaxf(lmax, bf2f(ch[j][e]));
    }

    // bitonic sort-64 of lane maxima, descending
    float v = lmax;
#pragma unroll
    for (int k = 2; k <= 64; k <<= 1) {
#pragma unroll
        for (int j = k >> 1; j >= 1; j >>= 1) {
            float o = __shfl_xor(v, j);
            bool lower = (l & j) == 0;
            bool descB = (l & k) == 0;
            v = (lower == descB) ? fmaxf(v, o) : fminf(v, o);
        }
    }
    const float T = __shfl(v, 47);   // >=48 elements >= T guaranteed

    // compact candidate indices (approx val >= T) into wave-private LDS
    int c = 0;
#pragma unroll
    for (int j = 0; j < 8; ++j) {
#pragma unroll
        for (int e = 0; e < 8; ++e) {
            bool p = (bf2f(ch[j][e]) >= T);
            u64 mask = __ballot(p);
            if (p) {
                int pos = c + (int)__popcll(mask & ((1ull << l) - 1ull));
                if (pos < CAP) cand[w][pos] = j * 512 + l * 8 + e;
            }
            c += (int)__popcll(mask);
        }
    }
    if (c > CAP) c = CAP;
    lds_fence();  // cand[] visible wave-wide

    // ---- 2. chunked coalesced gather + exact seq-fmaf dot ----
    u64 kreg[NCH];
#pragma unroll
    for (int r = 0; r < NCH; ++r) kreg[r] = 0ull;
    const int nchunk = (c + 31) >> 5;
    for (int ci = 0; ci < nchunk; ++ci) {
        const int cb = ci << 5;
        float acc = 0.0f;
#pragma unroll
        for (int half = 0; half < 2; ++half) {
            const float* base = half ? nv2 : nv1;
            // stage 32 candidate half-rows, coalesced (16 lanes per row)
#pragma unroll
            for (int it = 0; it < 8; ++it) {
                int f  = it * 64 + l;
                int r  = f >> 4;        // 0..31
                int j  = f & 15;
                int s  = cb + r;
                int n  = (s < c) ? cand[w][s] : 0;
                float4 vv = *(const float4*)(base + ((size_t)bt * NN + n) * DD + j * 4);
                *(float4*)&stg[w][r * STG_STRIDE + j * 4] = vv;
            }
            lds_fence();  // stage visible
            // exact dot, seq k order (lanes l and l+32 duplicate candidate l&31)
            const float* er = &embrow[w][half * 64];
            const int sr = (l & 31) * STG_STRIDE;
#pragma unroll
            for (int q = 0; q < 16; ++q) {
                float4 x = *(const float4*)&stg[w][sr + q * 4];
                acc = fmaf(er[q * 4 + 0], x.x, acc);
                acc = fmaf(er[q * 4 + 1], x.y, acc);
                acc = fmaf(er[q * 4 + 2], x.z, acc);
                acc = fmaf(er[q * 4 + 3], x.w, acc);
            }
            asm volatile("" ::: "memory");  // keep next stage's writes after reads
        }
        int s_me = cb + (l & 31);
        kreg[ci] = (s_me < c)
            ? (((u64)ord32(acc) << 32) | (u64)(0xFFFFFFFFu - (unsigned)cand[w][s_me]))
            : 0ull;
    }

    // ---- 3. pop exact top-32 (duplicate keys zero together -> correct) ----
    const int b = bt / NT;
    const int t = bt - b * NT;
    const size_t obase = (size_t)row * TOPK;
    for (int p = 0; p < TOPK; ++p) {
        u64 best = kreg[0];
#pragma unroll
        for (int r = 1; r < NCH; ++r)
            if (kreg[r] > best) best = kreg[r];
#pragma unroll
        for (int j = 1; j < 64; j <<= 1) {
            u64 o = __shfl_xor(best, j);
            if (o > best) best = o;
        }
        unsigned node = 0xFFFFFFFFu - (unsigned)(best & 0xFFFFFFFFull);
        if (l == 0) {
            out[IDX_OFF  + obase + p] = (float)node;
            out[BIDX_OFF + obase + p] = (float)b;
            out[TIDX_OFF + obase + p] = (float)t;
            widx[w][p] = (int)node;
        }
#pragma unroll
        for (int r = 0; r < NCH; ++r)
            if (kreg[r] == best) kreg[r] = 0ull;
    }
    lds_fence();  // widx visible wave-wide

    // ---- 4. winner gather + sel1/sel2 write (rows L2-hot; overwrites logits
    //         row `row` only — exclusively ours, already consumed) ----
#pragma unroll
    for (int it = 0; it < 8; ++it) {
        int p = it * 4 + (l >> 4);
        int j = l & 15;
        int n = widx[w][p] & (NN - 1);
        const float4 s1 = *(const float4*)(nv1 + ((size_t)bt * NN + n) * DD + j * 4);
        const float4 s2 = *(const float4*)(nv2 + ((size_t)bt * NN + n) * DD + j * 4);
        size_t o = (obase + p) * DD + j * 4;
        *(float4*)(out + SEL1_OFF + o) = s1;
        *(float4*)(out + SEL2_OFF + o) = s2;
    }
}

extern "C" void kernel_launch(void* const* d_in, const int* in_sizes, int n_in,
                              void* d_out, int out_size, void* d_ws, size_t ws_size,
                              hipStream_t stream) {
    const float* nv1 = (const float*)d_in[0];
    const float* nv2 = (const float*)d_in[1];
    const float* emb = (const float*)d_in[2];
    float* out = (float*)d_out;

    dim3 g1(32, BTc);
    k1_logits_bf16<<<g1, 256, 0, stream>>>(nv1, nv2, emb, (u16*)d_out);
    k2_fused<<<24576 / 4, 256, 0, stream>>>((const u16*)d_out, nv1, nv2, emb, out);
}

// Round 5
// 526.802 us; speedup vs baseline: 2.3730x; 2.3730x over previous
//
#include <hip/hip_runtime.h>
#include <stdint.h>

typedef unsigned long long u64;
typedef unsigned short u16;
typedef __attribute__((ext_vector_type(8))) short short8;
typedef __attribute__((ext_vector_type(4))) float f32x4;

// Problem constants
#define NB   16
#define NT   12
#define BTc  192     // NB*NT
#define NN   4096
#define DD   64
#define MM   128
#define TOPK 32
#define CAP  192     // candidate capacity (expected ~89, +7sigma margin; proven)
#define NCH  3       // CAP/64 pop registers

// d_out float offsets (outputs concatenated flat)
#define SEL1_OFF 0ULL
#define SEL2_OFF 50331648ULL
#define BIDX_OFF 100663296ULL
#define TIDX_OFF 101449728ULL
#define IDX_OFF  102236160ULL
// bf16 logits scratch (201.3 MB) occupies exactly the SEL1 float region.
// k2 reads row r's logits (8 KB) then writes row r's sel1 (same 8 KB) — per-row
// exclusive (row r owned by exactly one wave). Proven correct in R4.

__device__ __forceinline__ unsigned ord32(float f) {
    unsigned u = __float_as_uint(f);
    return (u & 0x80000000u) ? ~u : (u | 0x80000000u);
}
__device__ __forceinline__ u16 f2bf(float f) {   // RNE round to bf16
    unsigned u = __float_as_uint(f);
    unsigned r = u + 0x7FFFu + ((u >> 16) & 1u);
    return (u16)(r >> 16);
}
__device__ __forceinline__ float bf2f(short s) {
    return __uint_as_float(((unsigned)(u16)s) << 16);
}
__device__ __forceinline__ u64 pack4bf(float4 v) {
    return (u64)f2bf(v.x) | ((u64)f2bf(v.y) << 16) |
           ((u64)f2bf(v.z) << 32) | ((u64)f2bf(v.w) << 48);
}
__device__ __forceinline__ void lds_fence() {
    asm volatile("s_waitcnt lgkmcnt(0)" ::: "memory");
    __builtin_amdgcn_sched_barrier(0);   // rule #18
}

// ---------------------------------------------------------------------------
// K1: approx logits via bf16 MFMA (unchanged — at its 603 MB BW floor, ~105 us)
// ---------------------------------------------------------------------------
__global__ __launch_bounds__(256) void k1_logits_bf16(const float* __restrict__ nv1,
                                                      const float* __restrict__ nv2,
                                                      const float* __restrict__ emb,
                                                      u16* __restrict__ logitsB) {
    __shared__ u16 Als[128 * 128];   // [m][k] swizzled
    __shared__ u16 Bls[128 * 128];   // [n][k] swizzled (B^T layout)

    const int tid = threadIdx.x;
    const int nt  = blockIdx.x;      // 0..31
    const int bt  = blockIdx.y;      // 0..191
    const int n0  = nt * 128;

#pragma unroll
    for (int it = 0; it < 16; ++it) {
        int f4  = it * 256 + tid;
        int row = f4 >> 5;           // m
        int kq  = f4 & 31;
        float4 a = *(const float4*)(emb + row * 128 + kq * 4);
        int byte = row * 256 + ((kq * 8) ^ ((row & 7) << 4));
        *(u64*)((char*)Als + byte) = pack4bf(a);
    }
#pragma unroll
    for (int it = 0; it < 16; ++it) {
        int f4  = it * 256 + tid;
        int row = f4 >> 5;           // n within tile
        int kq  = f4 & 31;
        const float* src = (kq < 16)
            ? (nv1 + ((size_t)bt * NN + n0 + row) * DD + kq * 4)
            : (nv2 + ((size_t)bt * NN + n0 + row) * DD + (kq - 16) * 4);
        float4 bv = *(const float4*)src;
        int byte = row * 256 + ((kq * 8) ^ ((row & 7) << 4));
        *(u64*)((char*)Bls + byte) = pack4bf(bv);
    }
    __syncthreads();

    const int w  = tid >> 6;
    const int l  = tid & 63;
    const int mb = (w >> 1) * 64;
    const int nb = (w & 1) * 64;
    const int xr = (l & 7) << 4;

    f32x4 acc[4][4];
#pragma unroll
    for (int mi = 0; mi < 4; ++mi)
#pragma unroll
        for (int ni = 0; ni < 4; ++ni) acc[mi][ni] = {0.f, 0.f, 0.f, 0.f};

#pragma unroll
    for (int ks = 0; ks < 4; ++ks) {
        const int kb = (ks * 64 + (l >> 4) * 16) ^ xr;
        short8 a[4], b[4];
#pragma unroll
        for (int mi = 0; mi < 4; ++mi) {
            int row = mb + mi * 16 + (l & 15);
            a[mi] = *(const short8*)((const char*)Als + row * 256 + kb);
        }
#pragma unroll
        for (int ni = 0; ni < 4; ++ni) {
            int row = nb + ni * 16 + (l & 15);
            b[ni] = *(const short8*)((const char*)Bls + row * 256 + kb);
        }
#pragma unroll
        for (int mi = 0; mi < 4; ++mi)
#pragma unroll
            for (int ni = 0; ni < 4; ++ni)
                acc[mi][ni] = __builtin_amdgcn_mfma_f32_16x16x32_bf16(
                    a[mi], b[ni], acc[mi][ni], 0, 0, 0);
    }

    const size_t rbase = (size_t)bt * MM * NN;
#pragma unroll
    for (int mi = 0; mi < 4; ++mi)
#pragma unroll
        for (int ni = 0; ni < 4; ++ni) {
            int n = n0 + nb + ni * 16 + (l & 15);
#pragma unroll
            for (int r = 0; r < 4; ++r) {
                int m = mb + mi * 16 + (l >> 4) * 4 + r;
                logitsB[rbase + (size_t)m * NN + n] = f2bf(acc[mi][ni][r]);
            }
        }
}

// ---------------------------------------------------------------------------
// K2 (fused, v2): per row (one wave, wave-private LDS, no __syncthreads):
//  1. scan bf16 logits row, 48th-lane-max threshold -> candidate superset
//  2. DIRECT per-lane gather (lane = one candidate, 512B contiguous stream),
//     exact seq-fmaf fp32 dot (R2-proven)
//  3. pop exact top-32 (desc, ties -> lower index)
//  4. winner gather (L1/L2-hot) + sel1/sel2 write
// Grid XCD-swizzled: all 32 blocks of a bt land on one XCD -> 2.1 MB nv slice
// is L2-resident for the scattered gathers.
// ---------------------------------------------------------------------------
__global__ __launch_bounds__(256) void k2_fused(const u16* logitsB,
                                                const float* __restrict__ nv1,
                                                const float* __restrict__ nv2,
                                                const float* __restrict__ emb,
                                                float* out) {
    const int tid = threadIdx.x;
    const int l   = tid & 63;
    const int w   = tid >> 6;
    // bijective XCD-chunked swizzle: 6144 blocks = 8 XCDs x 768
    const int bid = (int)blockIdx.x;
    const int swz = (bid & 7) * 768 + (bid >> 3);
    const int row = swz * 4 + w;          // 0..24575
    const int bt  = row >> 7;
    const int m   = row & 127;
    const u16* src = logitsB + (size_t)row * NN;

    __shared__ int   cand[4][CAP];
    __shared__ float embrow[4][128];
    __shared__ int   widx[4][TOPK];

    embrow[w][l]      = emb[m * 128 + l];
    embrow[w][l + 64] = emb[m * 128 + 64 + l];

    // ---- 1. scan row (64 bf16 per lane in regs) + lane max ----
    short8 ch[8];
    float lmax = -INFINITY;
#pragma unroll
    for (int j = 0; j < 8; ++j) {
        ch[j] = *(const short8*)(src + j * 512 + l * 8);
#pragma unroll
        for (int e = 0; e < 8; ++e) lmax = fmaxf(lmax, bf2f(ch[j][e]));
    }

    // bitonic sort-64 of lane maxima, descending
    float v = lmax;
#pragma unroll
    for (int k = 2; k <= 64; k <<= 1) {
#pragma unroll
        for (int j = k >> 1; j >= 1; j >>= 1) {
            float o = __shfl_xor(v, j);
            bool lower = (l & j) == 0;
            bool descB = (l & k) == 0;
            v = (lower == descB) ? fmaxf(v, o) : fminf(v, o);
        }
    }
    const float T = __shfl(v, 47);   // >=48 elements >= T guaranteed

    // compact candidate indices (approx val >= T) into wave-private LDS
    int c = 0;
#pragma unroll
    for (int j = 0; j < 8; ++j) {
#pragma unroll
        for (int e = 0; e < 8; ++e) {
            bool p = (bf2f(ch[j][e]) >= T);
            u64 mask = __ballot(p);
            if (p) {
                int pos = c + (int)__popcll(mask & ((1ull << l) - 1ull));
                if (pos < CAP) cand[w][pos] = j * 512 + l * 8 + e;
            }
            c += (int)__popcll(mask);
        }
    }
    if (c > CAP) c = CAP;
    lds_fence();  // cand[] visible wave-wide

    // ---- 2. direct per-lane gather + exact seq-fmaf dot (R2 structure) ----
    u64 kreg[NCH];
#pragma unroll
    for (int s3 = 0; s3 < NCH; ++s3) {
        int s = s3 * 64 + l;
        u64 key = 0ull;
        if (s < c) {
            int n = cand[w][s];
            const float4* c1 = (const float4*)(nv1 + ((size_t)bt * NN + n) * DD);
            const float4* c2 = (const float4*)(nv2 + ((size_t)bt * NN + n) * DD);
            float acc = 0.f;
#pragma unroll
            for (int q = 0; q < 16; ++q) {
                float4 x = c1[q];
                acc = fmaf(embrow[w][q * 4 + 0], x.x, acc);
                acc = fmaf(embrow[w][q * 4 + 1], x.y, acc);
                acc = fmaf(embrow[w][q * 4 + 2], x.z, acc);
                acc = fmaf(embrow[w][q * 4 + 3], x.w, acc);
            }
#pragma unroll
            for (int q = 0; q < 16; ++q) {
                float4 x = c2[q];
                acc = fmaf(embrow[w][64 + q * 4 + 0], x.x, acc);
                acc = fmaf(embrow[w][64 + q * 4 + 1], x.y, acc);
                acc = fmaf(embrow[w][64 + q * 4 + 2], x.z, acc);
                acc = fmaf(embrow[w][64 + q * 4 + 3], x.w, acc);
            }
            key = ((u64)ord32(acc) << 32) | (u64)(0xFFFFFFFFu - (unsigned)n);
        }
        kreg[s3] = key;
    }

    // ---- 3. pop exact top-32 ----
    const int b = bt / NT;
    const int t = bt - b * NT;
    const size_t obase = (size_t)row * TOPK;
    for (int p = 0; p < TOPK; ++p) {
        u64 best = kreg[0];
#pragma unroll
        for (int r = 1; r < NCH; ++r)
            if (kreg[r] > best) best = kreg[r];
#pragma unroll
        for (int j = 1; j < 64; j <<= 1) {
            u64 o = __shfl_xor(best, j);
            if (o > best) best = o;
        }
        unsigned node = 0xFFFFFFFFu - (unsigned)(best & 0xFFFFFFFFull);
        if (l == 0) {
            out[IDX_OFF  + obase + p] = (float)node;
            out[BIDX_OFF + obase + p] = (float)b;
            out[TIDX_OFF + obase + p] = (float)t;
            widx[w][p] = (int)node;
        }
#pragma unroll
        for (int r = 0; r < NCH; ++r)
            if (kreg[r] == best) kreg[r] = 0ull;
    }
    lds_fence();  // widx visible wave-wide

    // ---- 4. winner gather + sel1/sel2 write (rows L1/L2-hot; overwrites
    //         logits row `row` only — exclusively ours, already consumed) ----
#pragma unroll
    for (int it = 0; it < 8; ++it) {
        int p = it * 4 + (l >> 4);
        int j = l & 15;
        int n = widx[w][p] & (NN - 1);
        const float4 s1 = *(const float4*)(nv1 + ((size_t)bt * NN + n) * DD + j * 4);
        const float4 s2 = *(const float4*)(nv2 + ((size_t)bt * NN + n) * DD + j * 4);
        size_t o = (obase + p) * DD + j * 4;
        *(float4*)(out + SEL1_OFF + o) = s1;
        *(float4*)(out + SEL2_OFF + o) = s2;
    }
}

extern "C" void kernel_launch(void* const* d_in, const int* in_sizes, int n_in,
                              void* d_out, int out_size, void* d_ws, size_t ws_size,
                              hipStream_t stream) {
    const float* nv1 = (const float*)d_in[0];
    const float* nv2 = (const float*)d_in[1];
    const float* emb = (const float*)d_in[2];
    float* out = (float*)d_out;

    dim3 g1(32, BTc);
    k1_logits_bf16<<<g1, 256, 0, stream>>>(nv1, nv2, emb, (u16*)d_out);
    k2_fused<<<24576 / 4, 256, 0, stream>>>((const u16*)d_out, nv1, nv2, emb, out);
}

// Round 6
// 410.112 us; speedup vs baseline: 3.0483x; 1.2845x over previous
//
#include <hip/hip_runtime.h>
#include <stdint.h>

typedef unsigned long long u64;
typedef unsigned short u16;
typedef __attribute__((ext_vector_type(8))) short short8;
typedef __attribute__((ext_vector_type(4))) float f32x4;

// Problem constants
#define NB   16
#define NT   12
#define BTc  192     // NB*NT
#define NN   4096
#define DD   64
#define MM   128
#define TOPK 32
#define KTH  36      // threshold = 36th-largest lane-max (margin 21 ranks >> bf16 err)
#define CAP  128     // candidate capacity (E[c]~53, P(c>128) ~ 7 sigma)

// d_out float offsets (outputs concatenated flat)
#define SEL1_OFF 0ULL
#define SEL2_OFF 50331648ULL
#define BIDX_OFF 100663296ULL
#define TIDX_OFF 101449728ULL
#define IDX_OFF  102236160ULL
// bf16 logits scratch (201.3 MB) occupies exactly the SEL1 float region.
// k2 reads row r's logits then writes row r's sel1 (same bytes) — per-row
// exclusive (row r owned by exactly one wave). Proven correct R4/R5.

__device__ __forceinline__ unsigned ord32(float f) {
    unsigned u = __float_as_uint(f);
    return (u & 0x80000000u) ? ~u : (u | 0x80000000u);
}
__device__ __forceinline__ u16 f2bf(float f) {   // RNE round to bf16
    unsigned u = __float_as_uint(f);
    unsigned r = u + 0x7FFFu + ((u >> 16) & 1u);
    return (u16)(r >> 16);
}
__device__ __forceinline__ float bf2f(short s) {
    return __uint_as_float(((unsigned)(u16)s) << 16);
}
__device__ __forceinline__ u64 pack4bf(float4 v) {
    return (u64)f2bf(v.x) | ((u64)f2bf(v.y) << 16) |
           ((u64)f2bf(v.z) << 32) | ((u64)f2bf(v.w) << 48);
}
__device__ __forceinline__ void lds_fence() {
    asm volatile("s_waitcnt lgkmcnt(0)" ::: "memory");
    __builtin_amdgcn_sched_barrier(0);   // rule #18
}
// descending bitonic sort of one u64 per lane across 64 lanes
__device__ __forceinline__ u64 sort64_desc(u64 v, int l) {
#pragma unroll
    for (int k = 2; k <= 64; k <<= 1) {
#pragma unroll
        for (int j = k >> 1; j >= 1; j >>= 1) {
            u64 o = __shfl_xor(v, j);
            bool takeMax = (((l & j) == 0) == ((l & k) == 0));
            v = takeMax ? (v > o ? v : o) : (v < o ? v : o);
        }
    }
    return v;
}

// ---------------------------------------------------------------------------
// K1: approx logits via bf16 MFMA (unchanged — near its 603 MB BW floor).
// ---------------------------------------------------------------------------
__global__ __launch_bounds__(256) void k1_logits_bf16(const float* __restrict__ nv1,
                                                      const float* __restrict__ nv2,
                                                      const float* __restrict__ emb,
                                                      u16* __restrict__ logitsB) {
    __shared__ u16 Als[128 * 128];   // [m][k] swizzled
    __shared__ u16 Bls[128 * 128];   // [n][k] swizzled (B^T layout)

    const int tid = threadIdx.x;
    const int nt  = blockIdx.x;      // 0..31
    const int bt  = blockIdx.y;      // 0..191
    const int n0  = nt * 128;

#pragma unroll
    for (int it = 0; it < 16; ++it) {
        int f4  = it * 256 + tid;
        int row = f4 >> 5;           // m
        int kq  = f4 & 31;
        float4 a = *(const float4*)(emb + row * 128 + kq * 4);
        int byte = row * 256 + ((kq * 8) ^ ((row & 7) << 4));
        *(u64*)((char*)Als + byte) = pack4bf(a);
    }
#pragma unroll
    for (int it = 0; it < 16; ++it) {
        int f4  = it * 256 + tid;
        int row = f4 >> 5;           // n within tile
        int kq  = f4 & 31;
        const float* src = (kq < 16)
            ? (nv1 + ((size_t)bt * NN + n0 + row) * DD + kq * 4)
            : (nv2 + ((size_t)bt * NN + n0 + row) * DD + (kq - 16) * 4);
        float4 bv = *(const float4*)src;
        int byte = row * 256 + ((kq * 8) ^ ((row & 7) << 4));
        *(u64*)((char*)Bls + byte) = pack4bf(bv);
    }
    __syncthreads();

    const int w  = tid >> 6;
    const int l  = tid & 63;
    const int mb = (w >> 1) * 64;
    const int nb = (w & 1) * 64;
    const int xr = (l & 7) << 4;

    f32x4 acc[4][4];
#pragma unroll
    for (int mi = 0; mi < 4; ++mi)
#pragma unroll
        for (int ni = 0; ni < 4; ++ni) acc[mi][ni] = {0.f, 0.f, 0.f, 0.f};

#pragma unroll
    for (int ks = 0; ks < 4; ++ks) {
        const int kb = (ks * 64 + (l >> 4) * 16) ^ xr;
        short8 a[4], b[4];
#pragma unroll
        for (int mi = 0; mi < 4; ++mi) {
            int row = mb + mi * 16 + (l & 15);
            a[mi] = *(const short8*)((const char*)Als + row * 256 + kb);
        }
#pragma unroll
        for (int ni = 0; ni < 4; ++ni) {
            int row = nb + ni * 16 + (l & 15);
            b[ni] = *(const short8*)((const char*)Bls + row * 256 + kb);
        }
#pragma unroll
        for (int mi = 0; mi < 4; ++mi)
#pragma unroll
            for (int ni = 0; ni < 4; ++ni)
                acc[mi][ni] = __builtin_amdgcn_mfma_f32_16x16x32_bf16(
                    a[mi], b[ni], acc[mi][ni], 0, 0, 0);
    }

    const size_t rbase = (size_t)bt * MM * NN;
#pragma unroll
    for (int mi = 0; mi < 4; ++mi)
#pragma unroll
        for (int ni = 0; ni < 4; ++ni) {
            int n = n0 + nb + ni * 16 + (l & 15);
#pragma unroll
            for (int r = 0; r < 4; ++r) {
                int m = mb + mi * 16 + (l >> 4) * 4 + r;
                logitsB[rbase + (size_t)m * NN + n] = f2bf(acc[mi][ni][r]);
            }
        }
}

// ---------------------------------------------------------------------------
// K2 (fused, v3): per row (one wave, wave-private, no __syncthreads):
//  1. scan bf16 logits row, 36th-lane-max threshold -> candidate superset
//  2. per-lane candidate: REGISTER-BATCHED half-row loads, exact seq-fmaf dot
//     (identical fp32 arithmetic order as R1-R5 — bit-stable ranking)
//  3. bitonic sort-64 (+merge if c>64) -> top-32 sorted desc in lanes 0..31
//  4. winner rows via shfl broadcast; register-batched gather; sel1/sel2 write
// Grid XCD-swizzled (bijective 8x768).
// ---------------------------------------------------------------------------
__global__ __launch_bounds__(256) void k2_fused(const u16* logitsB,
                                                const float* __restrict__ nv1,
                                                const float* __restrict__ nv2,
                                                const float* __restrict__ emb,
                                                float* out) {
    const int tid = threadIdx.x;
    const int l   = tid & 63;
    const int w   = tid >> 6;
    const int bid = (int)blockIdx.x;
    const int swz = (bid & 7) * 768 + (bid >> 3);
    const int row = swz * 4 + w;          // 0..24575
    const int bt  = row >> 7;
    const int m   = row & 127;
    const u16* src = logitsB + (size_t)row * NN;

    __shared__ int   cand[4][CAP];
    __shared__ float embrow[4][128];

    embrow[w][l]      = emb[m * 128 + l];
    embrow[w][l + 64] = emb[m * 128 + 64 + l];

    // ---- 1. scan row (64 bf16 per lane in regs) + lane max ----
    short8 ch[8];
    float lmax = -INFINITY;
#pragma unroll
    for (int j = 0; j < 8; ++j) {
        ch[j] = *(const short8*)(src + j * 512 + l * 8);
#pragma unroll
        for (int e = 0; e < 8; ++e) lmax = fmaxf(lmax, bf2f(ch[j][e]));
    }

    // bitonic sort-64 of lane maxima (descending), take 36th largest
    float v = lmax;
#pragma unroll
    for (int k = 2; k <= 64; k <<= 1) {
#pragma unroll
        for (int j = k >> 1; j >= 1; j >>= 1) {
            float o = __shfl_xor(v, j);
            bool takeMax = (((l & j) == 0) == ((l & k) == 0));
            v = takeMax ? fmaxf(v, o) : fminf(v, o);
        }
    }
    const float T = __shfl(v, KTH - 1);   // >= KTH elements >= T guaranteed

    // compact candidate indices (approx val >= T) into wave-private LDS
    int c = 0;
#pragma unroll
    for (int j = 0; j < 8; ++j) {
#pragma unroll
        for (int e = 0; e < 8; ++e) {
            bool p = (bf2f(ch[j][e]) >= T);
            u64 mask = __ballot(p);
            if (p) {
                int pos = c + (int)__popcll(mask & ((1ull << l) - 1ull));
                if (pos < CAP) cand[w][pos] = j * 512 + l * 8 + e;
            }
            c += (int)__popcll(mask);
        }
    }
    if (c > CAP) c = CAP;
    lds_fence();  // cand[] visible wave-wide

    // ---- 2. per-lane candidate dot: register-batched loads, exact seq order --
    u64 kreg[2] = {0ull, 0ull};
    const int nch = (c + 63) >> 6;   // 1 (96%) or 2
    for (int s3 = 0; s3 < nch; ++s3) {
        int s = s3 * 64 + l;
        if (s < c) {
            int n = cand[w][s];
            const float4* c1 = (const float4*)(nv1 + ((size_t)bt * NN + n) * DD);
            const float4* c2 = (const float4*)(nv2 + ((size_t)bt * NN + n) * DD);
            float4 r[16];
            float acc = 0.f;
            // nv1 half: batch-issue 16 loads, then the dependent chain
#pragma unroll
            for (int q = 0; q < 16; ++q) r[q] = c1[q];
#pragma unroll
            for (int q = 0; q < 16; ++q) {
                acc = fmaf(embrow[w][q * 4 + 0], r[q].x, acc);
                acc = fmaf(embrow[w][q * 4 + 1], r[q].y, acc);
                acc = fmaf(embrow[w][q * 4 + 2], r[q].z, acc);
                acc = fmaf(embrow[w][q * 4 + 3], r[q].w, acc);
            }
            // nv2 half
#pragma unroll
            for (int q = 0; q < 16; ++q) r[q] = c2[q];
#pragma unroll
            for (int q = 0; q < 16; ++q) {
                acc = fmaf(embrow[w][64 + q * 4 + 0], r[q].x, acc);
                acc = fmaf(embrow[w][64 + q * 4 + 1], r[q].y, acc);
                acc = fmaf(embrow[w][64 + q * 4 + 2], r[q].z, acc);
                acc = fmaf(embrow[w][64 + q * 4 + 3], r[q].w, acc);
            }
            kreg[s3] = ((u64)ord32(acc) << 32) | (u64)(0xFFFFFFFFu - (unsigned)n);
        }
    }

    // ---- 3. selection: sort desc; lanes 0..31 hold top-32 in order ----
    u64 top = sort64_desc(kreg[0], l);
    if (c > 64) {                         // wave-uniform branch (rare, ~4%)
        u64 B = sort64_desc(kreg[1], l);
        u64 rb = __shfl_xor(B, 63);       // reverse: lane l <- 63-l
        u64 M = top > rb ? top : rb;      // bitonic, contains top-64 of 128
#pragma unroll
        for (int j = 32; j >= 1; j >>= 1) {
            u64 o = __shfl_xor(M, j);
            M = ((l & j) == 0) ? (M > o ? M : o) : (M < o ? M : o);
        }
        top = M;
    }

    const int b = bt / NT;
    const int t = bt - b * NT;
    const size_t obase = (size_t)row * TOPK;
    const unsigned mynode = 0xFFFFFFFFu - (unsigned)(top & 0xFFFFFFFFull);
    if (l < TOPK) {
        out[IDX_OFF  + obase + l] = (float)mynode;
        out[BIDX_OFF + obase + l] = (float)b;
        out[TIDX_OFF + obase + l] = (float)t;
    }

    // ---- 4. winner gather (shfl broadcast of sorted keys), batched loads ----
    int myn[8];
#pragma unroll
    for (int it = 0; it < 8; ++it) {
        int p = it * 4 + (l >> 4);
        u64 kk = __shfl(top, p);
        myn[it] = (int)(0xFFFFFFFFu - (unsigned)(kk & 0xFFFFFFFFull)) & (NN - 1);
    }
    const int j4 = (l & 15) * 4;
    float4 s1[8], s2[8];
#pragma unroll
    for (int it = 0; it < 8; ++it)
        s1[it] = *(const float4*)(nv1 + ((size_t)bt * NN + myn[it]) * DD + j4);
#pragma unroll
    for (int it = 0; it < 8; ++it)
        s2[it] = *(const float4*)(nv2 + ((size_t)bt * NN + myn[it]) * DD + j4);
#pragma unroll
    for (int it = 0; it < 8; ++it) {
        int p = it * 4 + (l >> 4);
        size_t o = (obase + p) * DD + j4;
        *(float4*)(out + SEL1_OFF + o) = s1[it];
        *(float4*)(out + SEL2_OFF + o) = s2[it];
    }
}

extern "C" void kernel_launch(void* const* d_in, const int* in_sizes, int n_in,
                              void* d_out, int out_size, void* d_ws, size_t ws_size,
                              hipStream_t stream) {
    const float* nv1 = (const float*)d_in[0];
    const float* nv2 = (const float*)d_in[1];
    const float* emb = (const float*)d_in[2];
    float* out = (float*)d_out;

    dim3 g1(32, BTc);
    k1_logits_bf16<<<g1, 256, 0, stream>>>(nv1, nv2, emb, (u16*)d_out);
    k2_fused<<<24576 / 4, 256, 0, stream>>>((const u16*)d_out, nv1, nv2, emb, out);
}

// Round 7
// 402.454 us; speedup vs baseline: 3.1063x; 1.0190x over previous
//
#include <hip/hip_runtime.h>
#include <stdint.h>

typedef unsigned long long u64;
typedef unsigned short u16;
typedef __attribute__((ext_vector_type(8))) short short8;
typedef __attribute__((ext_vector_type(4))) float f32x4;

// Problem constants
#define NB   16
#define NT   12
#define BTc  192     // NB*NT
#define NN   4096
#define DD   64
#define MM   128
#define TOPK 32
#define KTH  36      // threshold = 36th-largest lane-max (margin ~21 ranks >> bf16 err)
#define CAP  128     // candidate capacity (E[c]~53, P(c>128) ~ 7 sigma)

// d_out float offsets (outputs concatenated flat)
#define SEL1_OFF 0ULL
#define SEL2_OFF 50331648ULL
#define BIDX_OFF 100663296ULL
#define TIDX_OFF 101449728ULL
#define IDX_OFF  102236160ULL
// bf16 logits scratch (201.3 MB) occupies exactly the SEL1 float region.
// k2 reads row r's logits then writes row r's sel1 (same bytes) — per-row
// exclusive (row r owned by exactly one wave). Proven correct R4-R6.

__device__ __forceinline__ unsigned ord32(float f) {
    unsigned u = __float_as_uint(f);
    return (u & 0x80000000u) ? ~u : (u | 0x80000000u);
}
__device__ __forceinline__ u16 f2bf(float f) {   // RNE round to bf16
    unsigned u = __float_as_uint(f);
    unsigned r = u + 0x7FFFu + ((u >> 16) & 1u);
    return (u16)(r >> 16);
}
__device__ __forceinline__ float bf2f(short s) {
    return __uint_as_float(((unsigned)(u16)s) << 16);
}
__device__ __forceinline__ u64 pack4bf(float4 v) {
    return (u64)f2bf(v.x) | ((u64)f2bf(v.y) << 16) |
           ((u64)f2bf(v.z) << 32) | ((u64)f2bf(v.w) << 48);
}
__device__ __forceinline__ void lds_fence() {
    asm volatile("s_waitcnt lgkmcnt(0)" ::: "memory");
    __builtin_amdgcn_sched_barrier(0);   // rule #18
}
__device__ __forceinline__ void nt_store4(float* p, float4 v) {
    f32x4 t = {v.x, v.y, v.z, v.w};
    __builtin_nontemporal_store(t, (f32x4*)p);
}
// descending bitonic sort of one u64 per lane across 64 lanes
__device__ __forceinline__ u64 sort64_desc(u64 v, int l) {
#pragma unroll
    for (int k = 2; k <= 64; k <<= 1) {
#pragma unroll
        for (int j = k >> 1; j >= 1; j >>= 1) {
            u64 o = __shfl_xor(v, j);
            bool takeMax = (((l & j) == 0) == ((l & k) == 0));
            v = takeMax ? (v > o ? v : o) : (v < o ? v : o);
        }
    }
    return v;
}

// ---------------------------------------------------------------------------
// K1: approx logits via bf16 MFMA (unchanged — near its 603 MB BW floor).
// ---------------------------------------------------------------------------
__global__ __launch_bounds__(256) void k1_logits_bf16(const float* __restrict__ nv1,
                                                      const float* __restrict__ nv2,
                                                      const float* __restrict__ emb,
                                                      u16* __restrict__ logitsB) {
    __shared__ u16 Als[128 * 128];   // [m][k] swizzled
    __shared__ u16 Bls[128 * 128];   // [n][k] swizzled (B^T layout)

    const int tid = threadIdx.x;
    const int nt  = blockIdx.x;      // 0..31
    const int bt  = blockIdx.y;      // 0..191
    const int n0  = nt * 128;

#pragma unroll
    for (int it = 0; it < 16; ++it) {
        int f4  = it * 256 + tid;
        int row = f4 >> 5;           // m
        int kq  = f4 & 31;
        float4 a = *(const float4*)(emb + row * 128 + kq * 4);
        int byte = row * 256 + ((kq * 8) ^ ((row & 7) << 4));
        *(u64*)((char*)Als + byte) = pack4bf(a);
    }
#pragma unroll
    for (int it = 0; it < 16; ++it) {
        int f4  = it * 256 + tid;
        int row = f4 >> 5;           // n within tile
        int kq  = f4 & 31;
        const float* src = (kq < 16)
            ? (nv1 + ((size_t)bt * NN + n0 + row) * DD + kq * 4)
            : (nv2 + ((size_t)bt * NN + n0 + row) * DD + (kq - 16) * 4);
        float4 bv = *(const float4*)src;
        int byte = row * 256 + ((kq * 8) ^ ((row & 7) << 4));
        *(u64*)((char*)Bls + byte) = pack4bf(bv);
    }
    __syncthreads();

    const int w  = tid >> 6;
    const int l  = tid & 63;
    const int mb = (w >> 1) * 64;
    const int nb = (w & 1) * 64;
    const int xr = (l & 7) << 4;

    f32x4 acc[4][4];
#pragma unroll
    for (int mi = 0; mi < 4; ++mi)
#pragma unroll
        for (int ni = 0; ni < 4; ++ni) acc[mi][ni] = {0.f, 0.f, 0.f, 0.f};

#pragma unroll
    for (int ks = 0; ks < 4; ++ks) {
        const int kb = (ks * 64 + (l >> 4) * 16) ^ xr;
        short8 a[4], b[4];
#pragma unroll
        for (int mi = 0; mi < 4; ++mi) {
            int row = mb + mi * 16 + (l & 15);
            a[mi] = *(const short8*)((const char*)Als + row * 256 + kb);
        }
#pragma unroll
        for (int ni = 0; ni < 4; ++ni) {
            int row = nb + ni * 16 + (l & 15);
            b[ni] = *(const short8*)((const char*)Bls + row * 256 + kb);
        }
#pragma unroll
        for (int mi = 0; mi < 4; ++mi)
#pragma unroll
            for (int ni = 0; ni < 4; ++ni)
                acc[mi][ni] = __builtin_amdgcn_mfma_f32_16x16x32_bf16(
                    a[mi], b[ni], acc[mi][ni], 0, 0, 0);
    }

    const size_t rbase = (size_t)bt * MM * NN;
#pragma unroll
    for (int mi = 0; mi < 4; ++mi)
#pragma unroll
        for (int ni = 0; ni < 4; ++ni) {
            int n = n0 + nb + ni * 16 + (l & 15);
#pragma unroll
            for (int r = 0; r < 4; ++r) {
                int m = mb + mi * 16 + (l >> 4) * 4 + r;
                logitsB[rbase + (size_t)m * NN + n] = f2bf(acc[mi][ni][r]);
            }
        }
}

// ---------------------------------------------------------------------------
// K2 (fused, v4): per row (one wave, wave-private, no __syncthreads):
//  1. scan bf16 logits row (NT loads, batched), 36th-lane-max threshold
//  2. per-lane candidate: FORCED 16-float4 batched loads (sched_barrier) +
//     exact seq-fmaf dot (identical fp32 order as R1-R6 — bit-stable)
//  3. bitonic sort-64 (+merge if c>64) -> top-32 sorted desc in lanes 0..31
//  4. winner rows via shfl; batched gather; NT sel1/sel2 stores
// Grid XCD-swizzled (bijective 8x768). __launch_bounds__(256,4): VGPR cap 128
// so the load batches actually stay in registers (R6: compiler cut to 60).
// ---------------------------------------------------------------------------
__global__ __launch_bounds__(256, 4) void k2_fused(const u16* logitsB,
                                                   const float* __restrict__ nv1,
                                                   const float* __restrict__ nv2,
                                                   const float* __restrict__ emb,
                                                   float* out) {
    const int tid = threadIdx.x;
    const int l   = tid & 63;
    const int w   = tid >> 6;
    const int bid = (int)blockIdx.x;
    const int swz = (bid & 7) * 768 + (bid >> 3);
    const int row = swz * 4 + w;          // 0..24575
    const int bt  = row >> 7;
    const int m   = row & 127;
    const u16* src = logitsB + (size_t)row * NN;

    __shared__ int   cand[4][CAP];
    __shared__ float embrow[4][128];

    embrow[w][l]      = emb[m * 128 + l];
    embrow[w][l + 64] = emb[m * 128 + 64 + l];

    // ---- 1. scan row: batch-issue all 8 NT loads, then reduce ----
    short8 ch[8];
#pragma unroll
    for (int j = 0; j < 8; ++j)
        ch[j] = __builtin_nontemporal_load((const short8*)(src + j * 512 + l * 8));
    __builtin_amdgcn_sched_barrier(0);

    float lmax = -INFINITY;
#pragma unroll
    for (int j = 0; j < 8; ++j)
#pragma unroll
        for (int e = 0; e < 8; ++e) lmax = fmaxf(lmax, bf2f(ch[j][e]));

    // bitonic sort-64 of lane maxima (descending), take KTH-th largest
    float v = lmax;
#pragma unroll
    for (int k = 2; k <= 64; k <<= 1) {
#pragma unroll
        for (int j = k >> 1; j >= 1; j >>= 1) {
            float o = __shfl_xor(v, j);
            bool takeMax = (((l & j) == 0) == ((l & k) == 0));
            v = takeMax ? fmaxf(v, o) : fminf(v, o);
        }
    }
    const float T = __shfl(v, KTH - 1);   // >= KTH elements >= T guaranteed

    // compact candidate indices (approx val >= T) into wave-private LDS
    int c = 0;
#pragma unroll
    for (int j = 0; j < 8; ++j) {
#pragma unroll
        for (int e = 0; e < 8; ++e) {
            bool p = (bf2f(ch[j][e]) >= T);
            u64 mask = __ballot(p);
            if (p) {
                int pos = c + (int)__popcll(mask & ((1ull << l) - 1ull));
                if (pos < CAP) cand[w][pos] = j * 512 + l * 8 + e;
            }
            c += (int)__popcll(mask);
        }
    }
    if (c > CAP) c = CAP;
    lds_fence();  // cand[] visible wave-wide

    // ---- 2. per-lane candidate dot: forced batched loads, exact seq order ----
    u64 kreg[2] = {0ull, 0ull};
    const int nch = (c + 63) >> 6;   // 1 (common) or 2
    for (int s3 = 0; s3 < nch; ++s3) {
        int s = s3 * 64 + l;
        if (s < c) {
            int n = cand[w][s];
            const float4* c1 = (const float4*)(nv1 + ((size_t)bt * NN + n) * DD);
            const float4* c2 = (const float4*)(nv2 + ((size_t)bt * NN + n) * DD);
            float4 r[16];
            float acc = 0.f;
            // nv1 half: batch-issue 16 loads (one latency exposure), then chain
#pragma unroll
            for (int q = 0; q < 16; ++q) r[q] = c1[q];
            __builtin_amdgcn_sched_barrier(0);
#pragma unroll
            for (int q = 0; q < 16; ++q) {
                acc = fmaf(embrow[w][q * 4 + 0], r[q].x, acc);
                acc = fmaf(embrow[w][q * 4 + 1], r[q].y, acc);
                acc = fmaf(embrow[w][q * 4 + 2], r[q].z, acc);
                acc = fmaf(embrow[w][q * 4 + 3], r[q].w, acc);
            }
            // nv2 half
#pragma unroll
            for (int q = 0; q < 16; ++q) r[q] = c2[q];
            __builtin_amdgcn_sched_barrier(0);
#pragma unroll
            for (int q = 0; q < 16; ++q) {
                acc = fmaf(embrow[w][64 + q * 4 + 0], r[q].x, acc);
                acc = fmaf(embrow[w][64 + q * 4 + 1], r[q].y, acc);
                acc = fmaf(embrow[w][64 + q * 4 + 2], r[q].z, acc);
                acc = fmaf(embrow[w][64 + q * 4 + 3], r[q].w, acc);
            }
            kreg[s3] = ((u64)ord32(acc) << 32) | (u64)(0xFFFFFFFFu - (unsigned)n);
        }
    }

    // ---- 3. selection: sort desc; lanes 0..31 hold top-32 in order ----
    u64 top = sort64_desc(kreg[0], l);
    if (c > 64) {                         // wave-uniform branch
        u64 B = sort64_desc(kreg[1], l);
        u64 rb = __shfl_xor(B, 63);       // reverse: lane l <- 63-l
        u64 M = top > rb ? top : rb;      // bitonic, contains top-64 of 128
#pragma unroll
        for (int j = 32; j >= 1; j >>= 1) {
            u64 o = __shfl_xor(M, j);
            M = ((l & j) == 0) ? (M > o ? M : o) : (M < o ? M : o);
        }
        top = M;
    }

    const int b = bt / NT;
    const int t = bt - b * NT;
    const size_t obase = (size_t)row * TOPK;
    const unsigned mynode = 0xFFFFFFFFu - (unsigned)(top & 0xFFFFFFFFull);
    if (l < TOPK) {
        __builtin_nontemporal_store((float)mynode, out + IDX_OFF  + obase + l);
        __builtin_nontemporal_store((float)b,      out + BIDX_OFF + obase + l);
        __builtin_nontemporal_store((float)t,      out + TIDX_OFF + obase + l);
    }

    // ---- 4. winner gather (shfl of sorted keys), batched loads, NT stores ----
    int myn[8];
#pragma unroll
    for (int it = 0; it < 8; ++it) {
        int p = it * 4 + (l >> 4);
        u64 kk = __shfl(top, p);
        myn[it] = (int)(0xFFFFFFFFu - (unsigned)(kk & 0xFFFFFFFFull)) & (NN - 1);
    }
    const int j4 = (l & 15) * 4;
    float4 s1[8], s2[8];
#pragma unroll
    for (int it = 0; it < 8; ++it)
        s1[it] = *(const float4*)(nv1 + ((size_t)bt * NN + myn[it]) * DD + j4);
#pragma unroll
    for (int it = 0; it < 8; ++it)
        s2[it] = *(const float4*)(nv2 + ((size_t)bt * NN + myn[it]) * DD + j4);
    __builtin_amdgcn_sched_barrier(0);
#pragma unroll
    for (int it = 0; it < 8; ++it) {
        int p = it * 4 + (l >> 4);
        size_t o = (obase + p) * DD + j4;
        nt_store4(out + SEL1_OFF + o, s1[it]);
        nt_store4(out + SEL2_OFF + o, s2[it]);
    }
}

extern "C" void kernel_launch(void* const* d_in, const int* in_sizes, int n_in,
                              void* d_out, int out_size, void* d_ws, size_t ws_size,
                              hipStream_t stream) {
    const float* nv1 = (const float*)d_in[0];
    const float* nv2 = (const float*)d_in[1];
    const float* emb = (const float*)d_in[2];
    float* out = (float*)d_out;

    dim3 g1(32, BTc);
    k1_logits_bf16<<<g1, 256, 0, stream>>>(nv1, nv2, emb, (u16*)d_out);
    k2_fused<<<24576 / 4, 256, 0, stream>>>((const u16*)d_out, nv1, nv2, emb, out);
}